// Round 1
// baseline (240.752 us; speedup 1.0000x reference)
//
#include <hip/hip_runtime.h>

#define MAXN 2048

typedef float f4v __attribute__((ext_vector_type(4)));
typedef int   i4v __attribute__((ext_vector_type(4)));

// Builds the deduplicated selection maps, exactly mirroring _fix_duplicates:
//   sel[j]   = rint(clip(w[j], 0, n-1))                 (round-half-even, like jnp.round)
//   dup[j]   = sel[j] seen at an earlier index
//   empties  = values never selected, consumed in DESCENDING order by dup rank
// block 0 -> column map (n=C), block 1 -> row map (n=R)
__global__ void build_map_kernel(const float* __restrict__ wc, const float* __restrict__ wr,
                                 int C, int R,
                                 int* __restrict__ colmap, int* __restrict__ rowmap) {
    const float* w;
    int n;
    int* outmap;
    if (blockIdx.x == 0) { w = wc; n = C; outmap = colmap; }
    else                 { w = wr; n = R; outmap = rowmap; }

    __shared__ int sel[MAXN];
    __shared__ int first[MAXN];
    __shared__ int emptyslot[MAXN];
    __shared__ int dts[256], ets[256];

    const int t = threadIdx.x;
    const int base = t * 8;           // contiguous 8-element segment per thread
    const float upper = (float)(n - 1);

    for (int k = 0; k < 8; k++) {
        int idx = base + k;
        if (idx < n) {
            float v = w[idx];
            v = fminf(fmaxf(v, 0.0f), upper);
            sel[idx]   = (int)rintf(v);      // RNE == jnp.round
            first[idx] = 0x7fffffff;
        }
    }
    __syncthreads();
    for (int k = 0; k < 8; k++) {
        int idx = base + k;
        if (idx < n) atomicMin(&first[sel[idx]], idx);
    }
    __syncthreads();

    int dflag[8], eflag[8];
    int dsum = 0, esum = 0;
    for (int k = 0; k < 8; k++) {
        int idx = base + k;
        if (idx < n) {
            dflag[k] = (first[sel[idx]] != idx) ? 1 : 0;   // non-first occurrence
            eflag[k] = (first[idx] == 0x7fffffff) ? 1 : 0; // value idx never used
        } else { dflag[k] = 0; eflag[k] = 0; }
        dsum += dflag[k]; esum += eflag[k];
    }

    // block-wide inclusive scans (Hillis-Steele over 256 per-thread sums)
    dts[t] = dsum; ets[t] = esum;
    __syncthreads();
    for (int off = 1; off < 256; off <<= 1) {
        int dv = 0, ev = 0;
        if (t >= off) { dv = dts[t - off]; ev = ets[t - off]; }
        __syncthreads();
        dts[t] += dv; ets[t] += ev;
        __syncthreads();
    }
    const int dexc = dts[t] - dsum;   // dups before my segment
    const int eexc = ets[t] - esum;   // empties (by value) below my segment
    const int E    = ets[255];        // total empties (== total dups)

    // scatter empties: value v with (# empties < v) = p goes to slot E-1-p (descending order)
    int erun = eexc;
    for (int k = 0; k < 8; k++) {
        int idx = base + k;
        if (idx < n && eflag[k]) emptyslot[E - 1 - erun] = idx;
        erun += eflag[k];
    }
    __syncthreads();

    // final map: k-th duplicate (index order) takes emptyslot[k]
    int drun = dexc;
    for (int k = 0; k < 8; k++) {
        int idx = base + k;
        if (idx < n) outmap[idx] = dflag[k] ? emptyslot[drun] : sel[idx];
        drun += dflag[k];
    }
}

// out[b, i, j] = x[b, rowmap[i], colmap[j]]
// WAVE-PRIVATE row staging: each 64-lane wave owns one output row and an 8 KB
// LDS slice. No __syncthreads() anywhere -- DS ops from a single wave complete
// in order, and the compiler inserts the lgkmcnt wait for the aliasing
// read-after-write. Each lane keeps 8 float4 loads in flight (vs 2 before),
// and waves slide past each other freely (pure TLP latency hiding).
__global__ __launch_bounds__(256) void gather_kernel(const float* __restrict__ x,
                              const int* __restrict__ rowmap,
                              const int* __restrict__ colmap,
                              float* __restrict__ out,
                              int R, int C, int nrows) {
    __shared__ float lds[4 * MAXN];   // 32 KB: one MAXN-float slice per wave
    const int t    = threadIdx.x;
    const int w    = t >> 6;
    const int lane = t & 63;

    const int r = (blockIdx.x << 2) + w;   // global output row handled by this wave
    if (r >= nrows) return;

    const int b  = r / R;
    const int i  = r - b * R;
    const int sr = rowmap[i];              // one dword per wave, broadcast via cache

    float*       my   = lds + w * MAXN;
    f4v*         my4  = (f4v*)my;
    const f4v*   src4 = (const f4v*)(x + ((size_t)b * R + sr) * (size_t)C);
    f4v*         dst4 = (f4v*)(out + (size_t)r * (size_t)C);
    const i4v*  cmap4 = (const i4v*)colmap;
    const int    n4   = C >> 2;            // 512 float4s per row

    // stage the source row into this wave's private LDS slice.
    // unroll 8 => 8 global_load_dwordx4 in flight per lane before the writes.
    #pragma unroll 8
    for (int k = lane; k < n4; k += 64) {
        my4[k] = src4[k];
    }

    // gather + coalesced nontemporal store (out is never re-read; keep it out
    // of L2/LLC so x stays resident there).
    #pragma unroll 8
    for (int k = lane; k < n4; k += 64) {
        i4v c = cmap4[k];
        f4v v;
        v.x = my[c.x];
        v.y = my[c.y];
        v.z = my[c.z];
        v.w = my[c.w];
        __builtin_nontemporal_store(v, dst4 + k);
    }
}

extern "C" void kernel_launch(void* const* d_in, const int* in_sizes, int n_in,
                              void* d_out, int out_size, void* d_ws, size_t ws_size,
                              hipStream_t stream) {
    const float* x  = (const float*)d_in[0];
    const float* wc = (const float*)d_in[1];
    const float* wr = (const float*)d_in[2];
    const int C = in_sizes[1];            // 2048
    const int R = in_sizes[2];            // 1024
    const int B = in_sizes[0] / (R * C);  // 16

    int* colmap = (int*)d_ws;
    int* rowmap = colmap + C;

    build_map_kernel<<<2, 256, 0, stream>>>(wc, wr, C, R, colmap, rowmap);

    const int nrows = B * R;              // 16384 output rows, one per wave
    gather_kernel<<<(nrows + 3) / 4, 256, 0, stream>>>(x, rowmap, colmap,
                                                       (float*)d_out, R, C, nrows);
}

// Round 2
// 236.610 us; speedup vs baseline: 1.0175x; 1.0175x over previous
//
#include <hip/hip_runtime.h>

#define MAXN 2048

typedef float f4v __attribute__((ext_vector_type(4)));
typedef int   i4v __attribute__((ext_vector_type(4)));

// Builds the deduplicated selection maps, exactly mirroring _fix_duplicates:
//   sel[j]   = rint(clip(w[j], 0, n-1))                 (round-half-even, like jnp.round)
//   dup[j]   = sel[j] seen at an earlier index
//   empties  = values never selected, consumed in DESCENDING order by dup rank
// block 0 -> column map (n=C), block 1 -> row map (n=R).
// For the row map we additionally emit the INVERSE permutation:
//   invrow[rowmap[i]] = i   (rowmap is a permutation after dedup, so this is exact)
__global__ void build_map_kernel(const float* __restrict__ wc, const float* __restrict__ wr,
                                 int C, int R,
                                 int* __restrict__ colmap, int* __restrict__ rowmap,
                                 int* __restrict__ invrow) {
    const float* w;
    int n;
    int* outmap;
    int* inv;
    if (blockIdx.x == 0) { w = wc; n = C; outmap = colmap; inv = nullptr; }
    else                 { w = wr; n = R; outmap = rowmap; inv = invrow; }

    __shared__ int sel[MAXN];
    __shared__ int first[MAXN];
    __shared__ int emptyslot[MAXN];
    __shared__ int dts[256], ets[256];

    const int t = threadIdx.x;
    const int base = t * 8;           // contiguous 8-element segment per thread
    const float upper = (float)(n - 1);

    for (int k = 0; k < 8; k++) {
        int idx = base + k;
        if (idx < n) {
            float v = w[idx];
            v = fminf(fmaxf(v, 0.0f), upper);
            sel[idx]   = (int)rintf(v);      // RNE == jnp.round
            first[idx] = 0x7fffffff;
        }
    }
    __syncthreads();
    for (int k = 0; k < 8; k++) {
        int idx = base + k;
        if (idx < n) atomicMin(&first[sel[idx]], idx);
    }
    __syncthreads();

    int dflag[8], eflag[8];
    int dsum = 0, esum = 0;
    for (int k = 0; k < 8; k++) {
        int idx = base + k;
        if (idx < n) {
            dflag[k] = (first[sel[idx]] != idx) ? 1 : 0;   // non-first occurrence
            eflag[k] = (first[idx] == 0x7fffffff) ? 1 : 0; // value idx never used
        } else { dflag[k] = 0; eflag[k] = 0; }
        dsum += dflag[k]; esum += eflag[k];
    }

    // block-wide inclusive scans (Hillis-Steele over 256 per-thread sums)
    dts[t] = dsum; ets[t] = esum;
    __syncthreads();
    for (int off = 1; off < 256; off <<= 1) {
        int dv = 0, ev = 0;
        if (t >= off) { dv = dts[t - off]; ev = ets[t - off]; }
        __syncthreads();
        dts[t] += dv; ets[t] += ev;
        __syncthreads();
    }
    const int dexc = dts[t] - dsum;   // dups before my segment
    const int eexc = ets[t] - esum;   // empties (by value) below my segment
    const int E    = ets[255];        // total empties (== total dups)

    // scatter empties: value v with (# empties < v) = p goes to slot E-1-p (descending order)
    int erun = eexc;
    for (int k = 0; k < 8; k++) {
        int idx = base + k;
        if (idx < n && eflag[k]) emptyslot[E - 1 - erun] = idx;
        erun += eflag[k];
    }
    __syncthreads();

    // final map: k-th duplicate (index order) takes emptyslot[k]
    int drun = dexc;
    for (int k = 0; k < 8; k++) {
        int idx = base + k;
        if (idx < n) {
            int val = dflag[k] ? emptyslot[drun] : sel[idx];
            outmap[idx] = val;
            if (inv) inv[val] = idx;   // inverse permutation (no races: val unique)
        }
        drun += dflag[k];
    }
}

// SEQUENTIAL-READ / SCATTER-WRITE formulation:
//   out[b, invrow[sr], j] = x[b, sr, colmap[j]]
// Block n's waves read source rows 4n..4n+3 -> the READ stream over x is
// globally sequential (DRAM page locality, prefetch-friendly, no demand-read
// stalls on random addresses). The row permutation is applied on the WRITE
// side: an 8 KB internally-contiguous store to a random row offset is posted
// into L2 write-back and drained lazily -- it cannot stall a wave.
// Column gather still goes through a wave-private LDS slice (no barriers;
// same-wave DS ops are ordered, compiler inserts the lgkm waits).
__global__ __launch_bounds__(256) void scatter_kernel(const float* __restrict__ x,
                              const int* __restrict__ invrow,
                              const int* __restrict__ colmap,
                              float* __restrict__ out,
                              int R, int C, int nrows) {
    __shared__ float lds[4 * MAXN];   // 32 KB: one MAXN-float slice per wave
    const int t    = threadIdx.x;
    const int w    = t >> 6;
    const int lane = t & 63;

    const int s = (blockIdx.x << 2) + w;   // global SOURCE row for this wave
    if (s >= nrows) return;

    const int b  = s / R;
    const int sr = s - b * R;
    const int di = invrow[sr];             // destination row index within batch

    float*       my   = lds + w * MAXN;
    f4v*         my4  = (f4v*)my;
    const f4v*   src4 = (const f4v*)(x + (size_t)s * (size_t)C);            // sequential
    f4v*         dst4 = (f4v*)(out + ((size_t)b * R + di) * (size_t)C);     // scattered row
    const i4v*  cmap4 = (const i4v*)colmap;
    const int    n4   = C >> 2;            // 512 float4s per row

    // stage the (sequentially-addressed) source row into this wave's LDS slice
    #pragma unroll 8
    for (int k = lane; k < n4; k += 64) {
        my4[k] = src4[k];
    }

    // column gather + coalesced store of the whole row to its permuted position
    #pragma unroll 8
    for (int k = lane; k < n4; k += 64) {
        i4v c = cmap4[k];
        f4v v;
        v.x = my[c.x];
        v.y = my[c.y];
        v.z = my[c.z];
        v.w = my[c.w];
        dst4[k] = v;
    }
}

extern "C" void kernel_launch(void* const* d_in, const int* in_sizes, int n_in,
                              void* d_out, int out_size, void* d_ws, size_t ws_size,
                              hipStream_t stream) {
    const float* x  = (const float*)d_in[0];
    const float* wc = (const float*)d_in[1];
    const float* wr = (const float*)d_in[2];
    const int C = in_sizes[1];            // 2048
    const int R = in_sizes[2];            // 1024
    const int B = in_sizes[0] / (R * C);  // 16

    int* colmap = (int*)d_ws;
    int* rowmap = colmap + C;
    int* invrow = rowmap + R;

    build_map_kernel<<<2, 256, 0, stream>>>(wc, wr, C, R, colmap, rowmap, invrow);

    const int nrows = B * R;              // 16384 source rows, one per wave
    scatter_kernel<<<(nrows + 3) / 4, 256, 0, stream>>>(x, invrow, colmap,
                                                        (float*)d_out, R, C, nrows);
}